// Round 6
// baseline (1134.705 us; speedup 1.0000x reference)
//
#include <hip/hip_runtime.h>

// meshLayer: out[n] = sum_{e: row[e]==n} sum_k ff[e,k] * (x[col[e]] @ W[k])
// CSR build -> scatter 32B edge records {col, ff[9]:bf16} -> fused kernel:
// per-wave chunked DMA of records to LDS (global_load_lds, 3-buf ring, 2 ahead),
// register-pipelined x-gathers, f32x2 FMA aggregation, then 16x16x32 bf16 MFMA.

#define CH 64
#define KB 9
#define LROW 584  // A-tile row stride in elems (1168 B, 16B aligned)

using f32x4  = __attribute__((ext_vector_type(4))) float;
using f32x2  = __attribute__((ext_vector_type(2))) float;
using bf16x8 = __attribute__((ext_vector_type(8))) short;
using u32x4  = __attribute__((ext_vector_type(4))) unsigned;
using u32x2  = __attribute__((ext_vector_type(2))) unsigned;

__device__ __forceinline__ float bf2f(unsigned short u) {
    unsigned v = ((unsigned)u) << 16;
    return __builtin_bit_cast(float, v);
}
__device__ __forceinline__ unsigned short f2bf(float f) {
    unsigned x = __builtin_bit_cast(unsigned, f);
    unsigned r = (x + 0x7FFFu + ((x >> 16) & 1u)) >> 16;   // RNE
    return (unsigned short)r;
}
__device__ __forceinline__ float lo16(unsigned v) {
    return __builtin_bit_cast(float, v << 16);
}
__device__ __forceinline__ float hi16(unsigned v) {
    return __builtin_bit_cast(float, v & 0xFFFF0000u);
}
__device__ __forceinline__ unsigned pkbf(float a, float b) {
    return (unsigned)f2bf(a) | ((unsigned)f2bf(b) << 16);
}
__device__ __forceinline__ void dma16(const void* g, void* l) {
    __builtin_amdgcn_global_load_lds(
        (const __attribute__((address_space(1))) unsigned int*)g,
        (__attribute__((address_space(3))) unsigned int*)l, 16, 0, 0);
}

// ---------------- CSR build ----------------

__global__ void k_hist_xconv(const int* __restrict__ row, int* __restrict__ cnt,
                             const float* __restrict__ x, unsigned short* __restrict__ xb,
                             int E, int Nn) {
    int stride = gridDim.x * blockDim.x;
    int gid = blockIdx.x * blockDim.x + threadIdx.x;
    for (int e = gid; e < E; e += stride) {
        int r = row[e];
        r = (r < 0) ? 0 : ((r >= Nn) ? Nn - 1 : r);
        atomicAdd(&cnt[r], 1);
    }
    int M = Nn * CH;
    for (int i = gid; i < M; i += stride) xb[i] = f2bf(x[i]);
}

__global__ void k_scan1(const int* __restrict__ cnt, int* __restrict__ loc,
                        int* __restrict__ csum, int Nn) {
    int t = threadIdx.x, lane = t & 63, w = t >> 6;
    int i = blockIdx.x * 256 + t;
    int v = (i < Nn) ? cnt[i] : 0;
    int x = v;
#pragma unroll
    for (int off = 1; off < 64; off <<= 1) {
        int y = __shfl_up(x, off);
        if (lane >= off) x += y;
    }
    __shared__ int ws[4], wo[4];
    if (lane == 63) ws[w] = x;
    __syncthreads();
    if (t == 0) {
        int s = 0;
        for (int j = 0; j < 4; j++) { int tv = ws[j]; wo[j] = s; s += tv; }
    }
    __syncthreads();
    x += wo[w];
    if (i < Nn) loc[i] = x - v;
    if (t == 255) csum[blockIdx.x] = x;
}

__global__ void k_scan2(const int* __restrict__ csum, int* __restrict__ coff, int nch) {
    int t = threadIdx.x, lane = t & 63, w = t >> 6;
    int v = (t < nch) ? csum[t] : 0;
    int x = v;
#pragma unroll
    for (int off = 1; off < 64; off <<= 1) {
        int y = __shfl_up(x, off);
        if (lane >= off) x += y;
    }
    __shared__ int ws[4], wo[4];
    if (lane == 63) ws[w] = x;
    __syncthreads();
    if (t == 0) {
        int s = 0;
        for (int j = 0; j < 4; j++) { int tv = ws[j]; wo[j] = s; s += tv; }
    }
    __syncthreads();
    x += wo[w];
    if (t < nch) coff[t] = x - v;
}

__global__ void k_scan3_wprep(const int* __restrict__ loc, const int* __restrict__ coff,
                              int* __restrict__ starts, int* __restrict__ cur,
                              const float* __restrict__ W, unsigned short* __restrict__ wfb,
                              int Nn, int E) {
    int i = blockIdx.x * 256 + threadIdx.x;
    if (i < Nn) {
        int st = loc[i] + coff[i >> 8];
        starts[i] = st;
        cur[i] = st;
    }
    if (i == 0) starts[Nn] = E;
    if (i < 72 * 64) {
        int f = i >> 6, lane = i & 63;
        int kstep = f >> 2, cb = f & 3;
        int q0 = kstep * 32 + (lane >> 4) * 8;
        int c = cb * 16 + (lane & 15);
        unsigned short* dst = wfb + (size_t)i * 8;
#pragma unroll
        for (int j = 0; j < 8; j++) dst[j] = f2bf(W[(q0 + j) * CH + c]);
    }
}

__global__ void k_scatter(const int* __restrict__ row, const int* __restrict__ col,
                          const float* __restrict__ ff, int* __restrict__ cur,
                          unsigned* __restrict__ rec, int E, int Nn) {
    int stride = gridDim.x * blockDim.x;
    for (int e = blockIdx.x * blockDim.x + threadIdx.x; e < E; e += stride) {
        int r = row[e];
        r = (r < 0) ? 0 : ((r >= Nn) ? Nn - 1 : r);
        int c = col[e];
        c = (c < 0) ? 0 : ((c >= Nn) ? Nn - 1 : c);
        const float* fp = ff + (size_t)e * KB;
        u32x4 v0, v1;
        v0.x = (unsigned)c;
        v0.y = pkbf(fp[0], fp[1]);
        v0.z = pkbf(fp[2], fp[3]);
        v0.w = pkbf(fp[4], fp[5]);
        v1.x = pkbf(fp[6], fp[7]);
        v1.y = (unsigned)f2bf(fp[8]);
        v1.z = 0u; v1.w = 0u;
        int pos = atomicAdd(&cur[r], 1);
        u32x4* dst = (u32x4*)(rec + (size_t)pos * 8);
        __builtin_nontemporal_store(v0, dst);
        __builtin_nontemporal_store(v1, dst + 1);
    }
}

// ---------------- fused aggregate + GEMM ----------------
// 256 threads = 4 waves; wave w owns nodes n0+4w..+3 (contiguous CSR segment).
// Records DMA'd to LDS in 64-edge chunks (3-buffer ring, issued 2 chunks ahead).
// Intra-chunk: 4-edge batches, rec ds_read + x-gather prefetched 1 batch ahead.

struct RecT { u32x4 a; u32x2 b; };

__global__ __launch_bounds__(256, 3) void k_fused(const unsigned short* __restrict__ xb,
                                                  const unsigned* __restrict__ rec,
                                                  const int* __restrict__ starts,
                                                  const unsigned short* __restrict__ wfb,
                                                  float* __restrict__ out, int Nn) {
    __shared__ unsigned short Ash[16 * LROW];       // 18,688 B
    __shared__ u32x4 recbuf[3 * 4 * 128];           // 24,576 B (3 bufs x 4 waves x 2KB)
    int t = threadIdx.x, w = t >> 6, lane = t & 63;
    int n0 = blockIdx.x * 16;
    int nb = n0 + w * 4;
    int w4 = w * 4;

    int segS = starts[nb];
    int bnd0 = starts[nb + 1];
    int bnd1 = starts[nb + 2];
    int bnd2 = starts[nb + 3];
    int segE = starts[nb + 4];

    f32x2 a01 = (f32x2)(0.0f), a23 = (f32x2)(0.0f), a45 = (f32x2)(0.0f), a67 = (f32x2)(0.0f);
    float a8 = 0.0f;
    int cnode = 0;
    int nextBnd = bnd0;

    auto flushNode = [&]() {
        unsigned short* d = &Ash[(w4 + cnode) * LROW + lane];
        d[0]   = f2bf(a01.x); d[64]  = f2bf(a01.y);
        d[128] = f2bf(a23.x); d[192] = f2bf(a23.y);
        d[256] = f2bf(a45.x); d[320] = f2bf(a45.y);
        d[384] = f2bf(a67.x); d[448] = f2bf(a67.y);
        d[512] = f2bf(a8);
        a01 = (f32x2)(0.0f); a23 = (f32x2)(0.0f);
        a45 = (f32x2)(0.0f); a67 = (f32x2)(0.0f); a8 = 0.0f;
        ++cnode;
        nextBnd = (cnode == 1) ? bnd1 : (cnode == 2) ? bnd2 : segE;
    };

    auto edge = [&](const RecT& r, unsigned short xvv, int q) {
        if (q < segE) {
            while (q == nextBnd) flushNode();
            float xf = bf2f(xvv);
            f32x2 xf2 = {xf, xf};
            f32x2 pr;
            pr.x = lo16(r.a.y); pr.y = hi16(r.a.y); a01 += pr * xf2;
            pr.x = lo16(r.a.z); pr.y = hi16(r.a.z); a23 += pr * xf2;
            pr.x = lo16(r.a.w); pr.y = hi16(r.a.w); a45 += pr * xf2;
            pr.x = lo16(r.b.x); pr.y = hi16(r.b.x); a67 += pr * xf2;
            a8 = fmaf(lo16(r.b.y), xf, a8);
        }
    };

    auto dmaChunk = [&](int cc) {
        const char* gs = (const char*)rec + ((size_t)(segS + (cc << 6))) * 32 + lane * 16;
        char* ls = (char*)recbuf + (((cc % 3) * 4 + w) * 2048);
        dma16(gs, ls);
        dma16(gs + 1024, ls + 1024);
    };

    if (segS < segE) {
        int m = segE - segS;
        int nchunks = (m + 63) >> 6;
        dmaChunk(0);
        if (nchunks > 1) dmaChunk(1);
        for (int c = 0; c < nchunks; ++c) {
            if (c == 0) {
                if (nchunks > 1) { asm volatile("s_waitcnt vmcnt(2)" ::: "memory"); }
                else             { asm volatile("s_waitcnt vmcnt(0)" ::: "memory"); }
            } else {
                asm volatile("s_waitcnt vmcnt(6)" ::: "memory");
            }
            __builtin_amdgcn_sched_barrier(0);
            const char* rb = (const char*)recbuf + (((c % 3) * 4 + w) * 2048);
            int base = segS + (c << 6);
            int lim = segE - base; if (lim > 64) lim = 64;
            int nbat = (lim + 3) >> 2;

            auto readRec = [&](int idx) {
                RecT r;
                r.a = *(const u32x4*)(rb + (idx & 63) * 32);
                r.b = *(const u32x2*)(rb + (idx & 63) * 32 + 16);
                return r;
            };
            auto gather4 = [&](const RecT* rr, unsigned short* xv) {
#pragma unroll
                for (int j = 0; j < 4; ++j) {
                    unsigned cc_ = rr[j].a.x;
                    cc_ = (cc_ < (unsigned)Nn) ? cc_ : 0u;
                    xv[j] = xb[(size_t)cc_ * CH + lane];
                }
            };

            RecT r0[4], r1[4];
            unsigned short xv0[4], xv1[4];
#pragma unroll
            for (int j = 0; j < 4; ++j) r0[j] = readRec(j);
            gather4(r0, xv0);

            int b = 0;
            while (true) {
                if (b == 2 && c + 2 < nchunks) dmaChunk(c + 2);
#pragma unroll
                for (int j = 0; j < 4; ++j) r1[j] = readRec((b + 1) * 4 + j);
                gather4(r1, xv1);
#pragma unroll
                for (int j = 0; j < 4; ++j) edge(r0[j], xv0[j], base + b * 4 + j);
                if (++b >= nbat) break;
#pragma unroll
                for (int j = 0; j < 4; ++j) r0[j] = readRec((b + 1) * 4 + j);
                gather4(r0, xv0);
#pragma unroll
                for (int j = 0; j < 4; ++j) edge(r1[j], xv1[j], base + b * 4 + j);
                if (++b >= nbat) break;
            }
        }
    }
    while (cnode < 4) flushNode();
    __syncthreads();

    // ---- GEMM: C[16x64] = A[16x576] @ W[576x64], wave w -> 16-col slice ----
    f32x4 C = {0, 0, 0, 0};
    int arow = lane & 15, g2 = lane >> 4;
    const unsigned short* ab = Ash + arow * LROW + g2 * 8;
    const bf16x8* wv = (const bf16x8*)wfb;
#pragma unroll
    for (int ks = 0; ks < 18; ++ks) {
        bf16x8 a = *(const bf16x8*)(ab + ks * 32);
        bf16x8 bfr = wv[(ks * 4 + w) * 64 + lane];
        C = __builtin_amdgcn_mfma_f32_16x16x32_bf16(a, bfr, C, 0, 0, 0);
    }
    float* ob = out + (size_t)n0 * CH + w * 16 + (lane & 15);
#pragma unroll
    for (int r = 0; r < 4; ++r) {
        int orow = g2 * 4 + r;
        if (n0 + orow < Nn) ob[orow * CH] = C[r];
    }
}

extern "C" void kernel_launch(void* const* d_in, const int* in_sizes, int n_in,
                              void* d_out, int out_size, void* d_ws, size_t ws_size,
                              hipStream_t stream) {
    const float* x   = (const float*)d_in[0];
    const int*   nbr = (const int*)d_in[1];
    const float* ff  = (const float*)d_in[2];
    const float* W   = (const float*)d_in[3];
    float* out = (float*)d_out;

    int Nn = in_sizes[0] / CH;   // 50000
    int E  = in_sizes[1] / 2;    // 1600000
    const int* row = nbr;
    const int* col = nbr + E;

    char* p = (char*)d_ws;
    auto alloc = [&](size_t bytes) -> void* {
        void* r = (void*)p;
        p += (bytes + 511) & ~(size_t)511;
        return r;
    };
    int* cnt    = (int*)alloc((size_t)Nn * 4);
    int* loc    = (int*)alloc((size_t)Nn * 4);
    int* csum   = (int*)alloc(1024);
    int* coff   = (int*)alloc(1024);
    int* starts = (int*)alloc((size_t)(Nn + 1) * 4);
    int* cur    = (int*)alloc((size_t)Nn * 4);
    unsigned* rec = (unsigned*)alloc((size_t)E * 32 + 4096);     // +pad for DMA overshoot
    unsigned short* xb  = (unsigned short*)alloc((size_t)Nn * CH * 2);
    unsigned short* wfb = (unsigned short*)alloc(72 * 64 * 8 * 2);

    (void)hipMemsetAsync(cnt, 0, (size_t)Nn * 4, stream);

    k_hist_xconv<<<2048, 256, 0, stream>>>(row, cnt, x, xb, E, Nn);

    int nch = (Nn + 255) / 256;  // 196
    k_scan1<<<nch, 256, 0, stream>>>(cnt, loc, csum, Nn);
    k_scan2<<<1, 256, 0, stream>>>(csum, coff, nch);
    k_scan3_wprep<<<nch, 256, 0, stream>>>(loc, coff, starts, cur, W, wfb, Nn, E);

    k_scatter<<<2048, 256, 0, stream>>>(row, col, ff, cur, rec, E, Nn);

    k_fused<<<(Nn + 15) / 16, 256, 0, stream>>>(xb, rec, starts, wfb, out, Nn);
}

// Round 7
// 838.694 us; speedup vs baseline: 1.3529x; 1.3529x over previous
//
#include <hip/hip_runtime.h>

// meshLayer: out[n] = sum_{e: row[e]==n} sum_k ff[e,k] * (x[col[e]] @ W[k])
// CSR build -> scatter 32B edge records {col, ff[9]:bf16} -> fused kernel:
// explicit 3-stage register pipeline (rec-load b+2 | x-gather b+1 | FMA b),
// then 16x16x32 bf16 MFMA GEMM against prepped W fragments.

#define CH 64
#define KB 9
#define LROW 584  // A-tile row stride in elems (1168 B, 16B aligned)

using f32x4  = __attribute__((ext_vector_type(4))) float;
using f32x2  = __attribute__((ext_vector_type(2))) float;
using bf16x8 = __attribute__((ext_vector_type(8))) short;
using u32x4  = __attribute__((ext_vector_type(4))) unsigned;
using u32x2  = __attribute__((ext_vector_type(2))) unsigned;

__device__ __forceinline__ float bf2f(unsigned short u) {
    unsigned v = ((unsigned)u) << 16;
    return __builtin_bit_cast(float, v);
}
__device__ __forceinline__ unsigned short f2bf(float f) {
    unsigned x = __builtin_bit_cast(unsigned, f);
    unsigned r = (x + 0x7FFFu + ((x >> 16) & 1u)) >> 16;   // RNE
    return (unsigned short)r;
}
__device__ __forceinline__ float lo16(unsigned v) {
    return __builtin_bit_cast(float, v << 16);
}
__device__ __forceinline__ float hi16(unsigned v) {
    return __builtin_bit_cast(float, v & 0xFFFF0000u);
}
__device__ __forceinline__ unsigned pkbf(float a, float b) {
    return (unsigned)f2bf(a) | ((unsigned)f2bf(b) << 16);
}

// ---------------- CSR build ----------------

__global__ void k_hist_xconv(const int* __restrict__ row, int* __restrict__ cnt,
                             const float* __restrict__ x, unsigned short* __restrict__ xb,
                             int E, int Nn) {
    int stride = gridDim.x * blockDim.x;
    int gid = blockIdx.x * blockDim.x + threadIdx.x;
    for (int e = gid; e < E; e += stride) {
        int r = row[e];
        r = (r < 0) ? 0 : ((r >= Nn) ? Nn - 1 : r);
        atomicAdd(&cnt[r], 1);
    }
    int M = Nn * CH;
    for (int i = gid; i < M; i += stride) xb[i] = f2bf(x[i]);
}

__global__ void k_scan1(const int* __restrict__ cnt, int* __restrict__ loc,
                        int* __restrict__ csum, int Nn) {
    int t = threadIdx.x, lane = t & 63, w = t >> 6;
    int i = blockIdx.x * 256 + t;
    int v = (i < Nn) ? cnt[i] : 0;
    int x = v;
#pragma unroll
    for (int off = 1; off < 64; off <<= 1) {
        int y = __shfl_up(x, off);
        if (lane >= off) x += y;
    }
    __shared__ int ws[4], wo[4];
    if (lane == 63) ws[w] = x;
    __syncthreads();
    if (t == 0) {
        int s = 0;
        for (int j = 0; j < 4; j++) { int tv = ws[j]; wo[j] = s; s += tv; }
    }
    __syncthreads();
    x += wo[w];
    if (i < Nn) loc[i] = x - v;
    if (t == 255) csum[blockIdx.x] = x;
}

__global__ void k_scan2(const int* __restrict__ csum, int* __restrict__ coff, int nch) {
    int t = threadIdx.x, lane = t & 63, w = t >> 6;
    int v = (t < nch) ? csum[t] : 0;
    int x = v;
#pragma unroll
    for (int off = 1; off < 64; off <<= 1) {
        int y = __shfl_up(x, off);
        if (lane >= off) x += y;
    }
    __shared__ int ws[4], wo[4];
    if (lane == 63) ws[w] = x;
    __syncthreads();
    if (t == 0) {
        int s = 0;
        for (int j = 0; j < 4; j++) { int tv = ws[j]; wo[j] = s; s += tv; }
    }
    __syncthreads();
    x += wo[w];
    if (t < nch) coff[t] = x - v;
}

__global__ void k_scan3_wprep(const int* __restrict__ loc, const int* __restrict__ coff,
                              int* __restrict__ starts, int* __restrict__ cur,
                              const float* __restrict__ W, unsigned short* __restrict__ wfb,
                              int Nn, int E) {
    int i = blockIdx.x * 256 + threadIdx.x;
    if (i < Nn) {
        int st = loc[i] + coff[i >> 8];
        starts[i] = st;
        cur[i] = st;
    }
    if (i == 0) starts[Nn] = E;
    if (i < 72 * 64) {
        int f = i >> 6, lane = i & 63;
        int kstep = f >> 2, cb = f & 3;
        int q0 = kstep * 32 + (lane >> 4) * 8;
        int c = cb * 16 + (lane & 15);
        unsigned short* dst = wfb + (size_t)i * 8;
#pragma unroll
        for (int j = 0; j < 8; j++) dst[j] = f2bf(W[(q0 + j) * CH + c]);
    }
}

__global__ void k_scatter(const int* __restrict__ row, const int* __restrict__ col,
                          const float* __restrict__ ff, int* __restrict__ cur,
                          unsigned* __restrict__ rec, int E, int Nn) {
    int stride = gridDim.x * blockDim.x;
    for (int e = blockIdx.x * blockDim.x + threadIdx.x; e < E; e += stride) {
        int r = row[e];
        r = (r < 0) ? 0 : ((r >= Nn) ? Nn - 1 : r);
        int c = col[e];
        c = (c < 0) ? 0 : ((c >= Nn) ? Nn - 1 : c);
        const float* fp = ff + (size_t)e * KB;
        u32x4 v0;
        u32x4 v1;
        v0.x = (unsigned)c;
        v0.y = pkbf(fp[0], fp[1]);
        v0.z = pkbf(fp[2], fp[3]);
        v0.w = pkbf(fp[4], fp[5]);
        v1.x = pkbf(fp[6], fp[7]);
        v1.y = (unsigned)f2bf(fp[8]);
        v1.z = 0u; v1.w = 0u;
        int pos = atomicAdd(&cur[r], 1);
        u32x4* dst = (u32x4*)(rec + (size_t)pos * 8);
        __builtin_nontemporal_store(v0, dst);
        __builtin_nontemporal_store(v1, dst + 1);
    }
}

// ---------------- fused aggregate + GEMM ----------------
// 256 threads = 4 waves; wave w owns nodes nb..nb+3 (contiguous CSR range).
// 3-stage pipeline over 4-edge batches: load recs for b+2, gather x for b+1,
// FMA batch b. Stage rotation manually unrolled -> all indices constant.

__global__ __launch_bounds__(256, 2) void k_fused(const unsigned short* __restrict__ xb,
                                                  const unsigned* __restrict__ rec,
                                                  const int* __restrict__ starts,
                                                  const unsigned short* __restrict__ wfb,
                                                  float* __restrict__ out, int Nn) {
    __shared__ unsigned short Ash[16 * LROW];       // 18,688 B
    int t = threadIdx.x, w = t >> 6, lane = t & 63;
    int n0 = blockIdx.x * 16;
    int nb = n0 + w * 4;
    int w4 = w * 4;

    int segS = starts[nb];
    int bnd0 = starts[nb + 1];
    int bnd1 = starts[nb + 2];
    int bnd2 = starts[nb + 3];
    int segE = starts[nb + 4];

    f32x2 a01 = {0.f, 0.f}, a23 = {0.f, 0.f}, a45 = {0.f, 0.f}, a67 = {0.f, 0.f};
    float a8 = 0.f;
    int cnode = 0;
    int nextBnd = bnd0;

    auto flushNode = [&]() {   // captures scalars + LDS base only
        unsigned short* d = &Ash[(w4 + cnode) * LROW + lane];
        d[0]   = f2bf(a01.x); d[64]  = f2bf(a01.y);
        d[128] = f2bf(a23.x); d[192] = f2bf(a23.y);
        d[256] = f2bf(a45.x); d[320] = f2bf(a45.y);
        d[384] = f2bf(a67.x); d[448] = f2bf(a67.y);
        d[512] = f2bf(a8);
        a01 = f32x2{0.f, 0.f}; a23 = f32x2{0.f, 0.f};
        a45 = f32x2{0.f, 0.f}; a67 = f32x2{0.f, 0.f}; a8 = 0.f;
        ++cnode;
        nextBnd = (cnode == 1) ? bnd1 : (cnode == 2) ? bnd2 : segE;
    };

    if (segS < segE) {
        int m = segE - segS;
        int nbat = (m + 3) >> 2;
        int segEm1 = segE - 1;
        const u32x4* rp4 = (const u32x4*)rec;

        u32x4 A0[4], A1[4], A2[4];
        u32x2 B0[4], B1[4], B2[4];
        unsigned short X0[4], X1[4], X2[4];
#pragma unroll
        for (int j = 0; j < 4; ++j) {
            A0[j] = (u32x4)(0u); A1[j] = (u32x4)(0u); A2[j] = (u32x4)(0u);
            B0[j] = (u32x2)(0u); B1[j] = (u32x2)(0u); B2[j] = (u32x2)(0u);
            X0[j] = 0; X1[j] = 0; X2[j] = 0;
        }

        // prologue: batch0 -> stage0, batch1 -> stage1, gather batch0
#pragma unroll
        for (int j = 0; j < 4; ++j) {
            int ei = segS + j; ei = (ei <= segEm1) ? ei : segEm1;
            A0[j] = __builtin_nontemporal_load(rp4 + (size_t)ei * 2);
            B0[j] = __builtin_nontemporal_load((const u32x2*)(rp4 + (size_t)ei * 2 + 1));
        }
        if (nbat > 1) {
#pragma unroll
            for (int j = 0; j < 4; ++j) {
                int ei = segS + 4 + j; ei = (ei <= segEm1) ? ei : segEm1;
                A1[j] = __builtin_nontemporal_load(rp4 + (size_t)ei * 2);
                B1[j] = __builtin_nontemporal_load((const u32x2*)(rp4 + (size_t)ei * 2 + 1));
            }
        }
#pragma unroll
        for (int j = 0; j < 4; ++j) {
            unsigned cc = A0[j].x; cc = (cc < (unsigned)Nn) ? cc : 0u;
            X0[j] = xb[(size_t)cc * CH + lane];
        }

        int bb = 0;
        while (true) {
            // ---- phase 0: load->S2, gather S1->X1, compute S0 ----
            {
                if (bb + 2 < nbat) {
                    int e2 = segS + ((bb + 2) << 2);
#pragma unroll
                    for (int j = 0; j < 4; ++j) {
                        int ei = e2 + j; ei = (ei <= segEm1) ? ei : segEm1;
                        A2[j] = __builtin_nontemporal_load(rp4 + (size_t)ei * 2);
                        B2[j] = __builtin_nontemporal_load((const u32x2*)(rp4 + (size_t)ei * 2 + 1));
                    }
                }
#pragma unroll
                for (int j = 0; j < 4; ++j) {
                    unsigned cc = A1[j].x; cc = (cc < (unsigned)Nn) ? cc : 0u;
                    X1[j] = xb[(size_t)cc * CH + lane];
                }
                int qb = segS + (bb << 2);
#pragma unroll
                for (int j = 0; j < 4; ++j) {
                    int q = qb + j;
                    if (q < segE) {
                        while (q == nextBnd) flushNode();
                        float xf = bf2f(X0[j]);
                        f32x2 xf2 = {xf, xf};
                        f32x2 pr;
                        pr.x = lo16(A0[j].y); pr.y = hi16(A0[j].y); a01 += pr * xf2;
                        pr.x = lo16(A0[j].z); pr.y = hi16(A0[j].z); a23 += pr * xf2;
                        pr.x = lo16(A0[j].w); pr.y = hi16(A0[j].w); a45 += pr * xf2;
                        pr.x = lo16(B0[j].x); pr.y = hi16(B0[j].x); a67 += pr * xf2;
                        a8 = fmaf(lo16(B0[j].y), xf, a8);
                    }
                }
            }
            if (++bb >= nbat) break;
            // ---- phase 1: load->S0, gather S2->X2, compute S1 ----
            {
                if (bb + 2 < nbat) {
                    int e2 = segS + ((bb + 2) << 2);
#pragma unroll
                    for (int j = 0; j < 4; ++j) {
                        int ei = e2 + j; ei = (ei <= segEm1) ? ei : segEm1;
                        A0[j] = __builtin_nontemporal_load(rp4 + (size_t)ei * 2);
                        B0[j] = __builtin_nontemporal_load((const u32x2*)(rp4 + (size_t)ei * 2 + 1));
                    }
                }
#pragma unroll
                for (int j = 0; j < 4; ++j) {
                    unsigned cc = A2[j].x; cc = (cc < (unsigned)Nn) ? cc : 0u;
                    X2[j] = xb[(size_t)cc * CH + lane];
                }
                int qb = segS + (bb << 2);
#pragma unroll
                for (int j = 0; j < 4; ++j) {
                    int q = qb + j;
                    if (q < segE) {
                        while (q == nextBnd) flushNode();
                        float xf = bf2f(X1[j]);
                        f32x2 xf2 = {xf, xf};
                        f32x2 pr;
                        pr.x = lo16(A1[j].y); pr.y = hi16(A1[j].y); a01 += pr * xf2;
                        pr.x = lo16(A1[j].z); pr.y = hi16(A1[j].z); a23 += pr * xf2;
                        pr.x = lo16(A1[j].w); pr.y = hi16(A1[j].w); a45 += pr * xf2;
                        pr.x = lo16(B1[j].x); pr.y = hi16(B1[j].x); a67 += pr * xf2;
                        a8 = fmaf(lo16(B1[j].y), xf, a8);
                    }
                }
            }
            if (++bb >= nbat) break;
            // ---- phase 2: load->S1, gather S0->X0, compute S2 ----
            {
                if (bb + 2 < nbat) {
                    int e2 = segS + ((bb + 2) << 2);
#pragma unroll
                    for (int j = 0; j < 4; ++j) {
                        int ei = e2 + j; ei = (ei <= segEm1) ? ei : segEm1;
                        A1[j] = __builtin_nontemporal_load(rp4 + (size_t)ei * 2);
                        B1[j] = __builtin_nontemporal_load((const u32x2*)(rp4 + (size_t)ei * 2 + 1));
                    }
                }
#pragma unroll
                for (int j = 0; j < 4; ++j) {
                    unsigned cc = A0[j].x; cc = (cc < (unsigned)Nn) ? cc : 0u;
                    X0[j] = xb[(size_t)cc * CH + lane];
                }
                int qb = segS + (bb << 2);
#pragma unroll
                for (int j = 0; j < 4; ++j) {
                    int q = qb + j;
                    if (q < segE) {
                        while (q == nextBnd) flushNode();
                        float xf = bf2f(X2[j]);
                        f32x2 xf2 = {xf, xf};
                        f32x2 pr;
                        pr.x = lo16(A2[j].y); pr.y = hi16(A2[j].y); a01 += pr * xf2;
                        pr.x = lo16(A2[j].z); pr.y = hi16(A2[j].z); a23 += pr * xf2;
                        pr.x = lo16(A2[j].w); pr.y = hi16(A2[j].w); a45 += pr * xf2;
                        pr.x = lo16(B2[j].x); pr.y = hi16(B2[j].x); a67 += pr * xf2;
                        a8 = fmaf(lo16(B2[j].y), xf, a8);
                    }
                }
            }
            if (++bb >= nbat) break;
        }
    }
    while (cnode < 4) flushNode();
    __syncthreads();

    // ---- GEMM: C[16x64] = A[16x576] @ W[576x64], wave w -> 16-col slice ----
    f32x4 C = {0, 0, 0, 0};
    int arow = lane & 15, g2 = lane >> 4;
    const unsigned short* ab = Ash + arow * LROW + g2 * 8;
    const bf16x8* wv = (const bf16x8*)wfb;
#pragma unroll
    for (int ks = 0; ks < 18; ++ks) {
        bf16x8 a = *(const bf16x8*)(ab + ks * 32);
        bf16x8 bfr = wv[(ks * 4 + w) * 64 + lane];
        C = __builtin_amdgcn_mfma_f32_16x16x32_bf16(a, bfr, C, 0, 0, 0);
    }
    float* ob = out + (size_t)n0 * CH + w * 16 + (lane & 15);
#pragma unroll
    for (int r = 0; r < 4; ++r) {
        int orow = g2 * 4 + r;
        if (n0 + orow < Nn) ob[orow * CH] = C[r];
    }
}

extern "C" void kernel_launch(void* const* d_in, const int* in_sizes, int n_in,
                              void* d_out, int out_size, void* d_ws, size_t ws_size,
                              hipStream_t stream) {
    const float* x   = (const float*)d_in[0];
    const int*   nbr = (const int*)d_in[1];
    const float* ff  = (const float*)d_in[2];
    const float* W   = (const float*)d_in[3];
    float* out = (float*)d_out;

    int Nn = in_sizes[0] / CH;   // 50000
    int E  = in_sizes[1] / 2;    // 1600000
    const int* row = nbr;
    const int* col = nbr + E;

    char* p = (char*)d_ws;
    auto alloc = [&](size_t bytes) -> void* {
        void* r = (void*)p;
        p += (bytes + 511) & ~(size_t)511;
        return r;
    };
    int* cnt    = (int*)alloc((size_t)Nn * 4);
    int* loc    = (int*)alloc((size_t)Nn * 4);
    int* csum   = (int*)alloc(1024);
    int* coff   = (int*)alloc(1024);
    int* starts = (int*)alloc((size_t)(Nn + 1) * 4);
    int* cur    = (int*)alloc((size_t)Nn * 4);
    unsigned* rec = (unsigned*)alloc((size_t)E * 32 + 4096);     // +pad for tail clamp
    unsigned short* xb  = (unsigned short*)alloc((size_t)Nn * CH * 2);
    unsigned short* wfb = (unsigned short*)alloc(72 * 64 * 8 * 2);

    (void)hipMemsetAsync(cnt, 0, (size_t)Nn * 4, stream);

    k_hist_xconv<<<2048, 256, 0, stream>>>(row, cnt, x, xb, E, Nn);

    int nch = (Nn + 255) / 256;  // 196
    k_scan1<<<nch, 256, 0, stream>>>(cnt, loc, csum, Nn);
    k_scan2<<<1, 256, 0, stream>>>(csum, coff, nch);
    k_scan3_wprep<<<nch, 256, 0, stream>>>(loc, coff, starts, cur, W, wfb, Nn, E);

    k_scatter<<<2048, 256, 0, stream>>>(row, col, ff, cur, rec, E, Nn);

    k_fused<<<(Nn + 15) / 16, 256, 0, stream>>>(xb, rec, starts, wfb, out, Nn);
}

// Round 10
// 383.781 us; speedup vs baseline: 2.9567x; 2.1853x over previous
//
#include <hip/hip_runtime.h>

// meshLayer: out[n] = sum_{e: row[e]==n} sum_k ff[e,k] * (x[col[e]] @ W[k])
// CSR build -> scatter 32B edge records {col, ff[9]:bf16} -> fused kernel:
// per-wave DMA ring (global_load_lds, 3 x 32-edge chunks, 2 ahead) feeding a
// named-scalar double-buffered consume loop (NO arrays -> no scratch), then
// 16x16x32 bf16 MFMA GEMM against prepped W fragments.

#define CH 64
#define KB 9
#define LROW 584  // A-tile row stride in elems (1168 B, 16B aligned)

using f32x4  = __attribute__((ext_vector_type(4))) float;
using bf16x8 = __attribute__((ext_vector_type(8))) short;
using u32x4  = __attribute__((ext_vector_type(4))) unsigned;
using u32x2  = __attribute__((ext_vector_type(2))) unsigned;

__device__ __forceinline__ float bf2f(unsigned short u) {
    unsigned v = ((unsigned)u) << 16;
    return __builtin_bit_cast(float, v);
}
__device__ __forceinline__ unsigned short f2bf(float f) {
    unsigned x = __builtin_bit_cast(unsigned, f);
    unsigned r = (x + 0x7FFFu + ((x >> 16) & 1u)) >> 16;   // RNE
    return (unsigned short)r;
}
__device__ __forceinline__ float lo16(unsigned v) {
    return __builtin_bit_cast(float, v << 16);
}
__device__ __forceinline__ float hi16(unsigned v) {
    return __builtin_bit_cast(float, v & 0xFFFF0000u);
}
__device__ __forceinline__ unsigned pkbf(float a, float b) {
    return (unsigned)f2bf(a) | ((unsigned)f2bf(b) << 16);
}
__device__ __forceinline__ void dma16(const void* g, void* l) {
    __builtin_amdgcn_global_load_lds(
        (const __attribute__((address_space(1))) unsigned int*)g,
        (__attribute__((address_space(3))) unsigned int*)l, 16, 0, 0);
}

// ---------------- CSR build ----------------

__global__ void k_hist_xconv(const int* __restrict__ row, int* __restrict__ cnt,
                             const float* __restrict__ x, unsigned short* __restrict__ xb,
                             int E, int Nn) {
    int stride = gridDim.x * blockDim.x;
    int gid = blockIdx.x * blockDim.x + threadIdx.x;
    for (int e = gid; e < E; e += stride) {
        int r = row[e];
        r = (r < 0) ? 0 : ((r >= Nn) ? Nn - 1 : r);
        atomicAdd(&cnt[r], 1);
    }
    int M = Nn * CH;
    for (int i = gid; i < M; i += stride) xb[i] = f2bf(x[i]);
}

__global__ void k_scan1(const int* __restrict__ cnt, int* __restrict__ loc,
                        int* __restrict__ csum, int Nn) {
    int t = threadIdx.x, lane = t & 63, w = t >> 6;
    int i = blockIdx.x * 256 + t;
    int v = (i < Nn) ? cnt[i] : 0;
    int x = v;
#pragma unroll
    for (int off = 1; off < 64; off <<= 1) {
        int y = __shfl_up(x, off);
        if (lane >= off) x += y;
    }
    __shared__ int ws[4], wo[4];
    if (lane == 63) ws[w] = x;
    __syncthreads();
    if (t == 0) {
        int s = 0;
        for (int j = 0; j < 4; j++) { int tv = ws[j]; wo[j] = s; s += tv; }
    }
    __syncthreads();
    x += wo[w];
    if (i < Nn) loc[i] = x - v;
    if (t == 255) csum[blockIdx.x] = x;
}

__global__ void k_scan2(const int* __restrict__ csum, int* __restrict__ coff, int nch) {
    int t = threadIdx.x, lane = t & 63, w = t >> 6;
    int v = (t < nch) ? csum[t] : 0;
    int x = v;
#pragma unroll
    for (int off = 1; off < 64; off <<= 1) {
        int y = __shfl_up(x, off);
        if (lane >= off) x += y;
    }
    __shared__ int ws[4], wo[4];
    if (lane == 63) ws[w] = x;
    __syncthreads();
    if (t == 0) {
        int s = 0;
        for (int j = 0; j < 4; j++) { int tv = ws[j]; wo[j] = s; s += tv; }
    }
    __syncthreads();
    x += wo[w];
    if (t < nch) coff[t] = x - v;
}

__global__ void k_scan3_wprep(const int* __restrict__ loc, const int* __restrict__ coff,
                              int* __restrict__ starts, int* __restrict__ cur,
                              const float* __restrict__ W, unsigned short* __restrict__ wfb,
                              int Nn, int E) {
    int i = blockIdx.x * 256 + threadIdx.x;
    if (i < Nn) {
        int st = loc[i] + coff[i >> 8];
        starts[i] = st;
        cur[i] = st;
    }
    if (i == 0) starts[Nn] = E;
    if (i < 72 * 64) {
        int f = i >> 6, lane = i & 63;
        int kstep = f >> 2, cb = f & 3;
        int q0 = kstep * 32 + (lane >> 4) * 8;
        int c = cb * 16 + (lane & 15);
        unsigned short* dst = wfb + (size_t)i * 8;
#pragma unroll
        for (int j = 0; j < 8; j++) dst[j] = f2bf(W[(q0 + j) * CH + c]);
    }
}

__global__ void k_scatter(const int* __restrict__ row, const int* __restrict__ col,
                          const float* __restrict__ ff, int* __restrict__ cur,
                          unsigned* __restrict__ rec, int E, int Nn) {
    int stride = gridDim.x * blockDim.x;
    for (int e = blockIdx.x * blockDim.x + threadIdx.x; e < E; e += stride) {
        int r = row[e];
        r = (r < 0) ? 0 : ((r >= Nn) ? Nn - 1 : r);
        int c = col[e];
        c = (c < 0) ? 0 : ((c >= Nn) ? Nn - 1 : c);
        const float* fp = ff + (size_t)e * KB;
        u32x4 v0;
        u32x4 v1;
        v0.x = (unsigned)c;
        v0.y = pkbf(fp[0], fp[1]);
        v0.z = pkbf(fp[2], fp[3]);
        v0.w = pkbf(fp[4], fp[5]);
        v1.x = pkbf(fp[6], fp[7]);
        v1.y = (unsigned)f2bf(fp[8]);
        v1.z = 0u; v1.w = 0u;
        int pos = atomicAdd(&cur[r], 1);
        u32x4* dst = (u32x4*)(rec + (size_t)pos * 8);
        __builtin_nontemporal_store(v0, dst);
        __builtin_nontemporal_store(v1, dst + 1);
    }
}

// ---------------- fused aggregate + GEMM ----------------

__device__ __forceinline__ void flushA(unsigned short* Ash, int w4, int lane,
        float& a0, float& a1, float& a2, float& a3, float& a4,
        float& a5, float& a6, float& a7, float& a8,
        int& cnode, int& nextBnd, int bnd1, int bnd2, int segE) {
    unsigned short* d = &Ash[(w4 + cnode) * LROW + lane];
    d[0]   = f2bf(a0); d[64]  = f2bf(a1); d[128] = f2bf(a2); d[192] = f2bf(a3);
    d[256] = f2bf(a4); d[320] = f2bf(a5); d[384] = f2bf(a6); d[448] = f2bf(a7);
    d[512] = f2bf(a8);
    a0 = 0.f; a1 = 0.f; a2 = 0.f; a3 = 0.f; a4 = 0.f;
    a5 = 0.f; a6 = 0.f; a7 = 0.f; a8 = 0.f;
    ++cnode;
    nextBnd = (cnode == 1) ? bnd1 : (cnode == 2) ? bnd2 : segE;
}

__device__ __forceinline__ void edge9(u32x4 ra, u32x2 rb, unsigned short xv, int q,
        unsigned short* Ash, int w4, int lane,
        float& a0, float& a1, float& a2, float& a3, float& a4,
        float& a5, float& a6, float& a7, float& a8,
        int& cnode, int& nextBnd, int bnd1, int bnd2, int segE) {
    if (q < segE) {
        while (q == nextBnd)
            flushA(Ash, w4, lane, a0, a1, a2, a3, a4, a5, a6, a7, a8,
                   cnode, nextBnd, bnd1, bnd2, segE);
        float xf = bf2f(xv);
        a0 = fmaf(lo16(ra.y), xf, a0);
        a1 = fmaf(hi16(ra.y), xf, a1);
        a2 = fmaf(lo16(ra.z), xf, a2);
        a3 = fmaf(hi16(ra.z), xf, a3);
        a4 = fmaf(lo16(ra.w), xf, a4);
        a5 = fmaf(hi16(ra.w), xf, a5);
        a6 = fmaf(lo16(rb.x), xf, a6);
        a7 = fmaf(hi16(rb.x), xf, a7);
        a8 = fmaf(lo16(rb.y), xf, a8);
    }
}

// 256 threads = 4 waves; wave w owns nodes nb..nb+3 (contiguous CSR range).
// Records stream through a per-wave 3 x 32-edge LDS ring filled by
// global_load_lds issued 2 chunks ahead; consume loop is the round-4 proven
// named-scalar double-buffer (read batch b+1 | gather b+1 | FMA batch b).
__global__ __launch_bounds__(256, 2) void k_fused(const unsigned short* __restrict__ xb,
                                                  const unsigned* __restrict__ rec,
                                                  const int* __restrict__ starts,
                                                  const unsigned short* __restrict__ wfb,
                                                  float* __restrict__ out, int Nn) {
    __shared__ unsigned short Ash[16 * LROW];   // 18,688 B
    __shared__ u32x4 recbuf[768];               // 12,288 B = 3 bufs x 4 waves x 1KB
    int t = threadIdx.x, w = t >> 6, lane = t & 63;
    int n0 = blockIdx.x * 16;
    int nb = n0 + w * 4;
    int w4 = w * 4;

    int segS = starts[nb];
    int bnd0 = starts[nb + 1];
    int bnd1 = starts[nb + 2];
    int bnd2 = starts[nb + 3];
    int segE = starts[nb + 4];

    float a0 = 0.f, a1 = 0.f, a2 = 0.f, a3 = 0.f, a4 = 0.f;
    float a5 = 0.f, a6 = 0.f, a7 = 0.f, a8 = 0.f;
    int cnode = 0;
    int nextBnd = bnd0;

    if (segS < segE) {
        int m = segE - segS;
        int nchunks = (m + 31) >> 5;

        // prologue DMA: chunk 0 (+1)
        {
            const char* gs = (const char*)rec + ((size_t)segS) * 32 + lane * 16;
            char* ls = (char*)recbuf + (w << 10);
            dma16(gs, ls);
        }
        if (nchunks > 1) {
            const char* gs = (const char*)rec + ((size_t)(segS + 32)) * 32 + lane * 16;
            char* ls = (char*)recbuf + ((4 + w) << 10);
            dma16(gs, ls);
        }

        for (int c = 0; c < nchunks; ++c) {
            if (c == 0) {
                if (nchunks > 1) { asm volatile("s_waitcnt vmcnt(1)" ::: "memory"); }
                else             { asm volatile("s_waitcnt vmcnt(0)" ::: "memory"); }
            } else {
                asm volatile("s_waitcnt vmcnt(5)" ::: "memory");
            }
            __builtin_amdgcn_sched_barrier(0);
            const char* rb = (const char*)recbuf + (((c % 3) * 4 + w) << 10);
            int base = segS + (c << 5);
            int lim = segE - base; if (lim > 32) lim = 32;
            int nbat = (lim + 3) >> 2;

            u32x4 Ra0, Ra1, Ra2, Ra3, Sa0, Sa1, Sa2, Sa3;
            u32x2 Rb0, Rb1, Rb2, Rb3, Sb0, Sb1, Sb2, Sb3;
            unsigned short x0, x1, x2, x3, y0, y1, y2, y3;

            // prologue: batch 0 -> R, gather -> x
            Ra0 = *(const u32x4*)(rb + 0);   Rb0 = *(const u32x2*)(rb + 16);
            Ra1 = *(const u32x4*)(rb + 32);  Rb1 = *(const u32x2*)(rb + 48);
            Ra2 = *(const u32x4*)(rb + 64);  Rb2 = *(const u32x2*)(rb + 80);
            Ra3 = *(const u32x4*)(rb + 96);  Rb3 = *(const u32x2*)(rb + 112);
            {
                unsigned c0 = Ra0.x; c0 = (c0 < (unsigned)Nn) ? c0 : 0u;
                unsigned c1 = Ra1.x; c1 = (c1 < (unsigned)Nn) ? c1 : 0u;
                unsigned c2 = Ra2.x; c2 = (c2 < (unsigned)Nn) ? c2 : 0u;
                unsigned c3 = Ra3.x; c3 = (c3 < (unsigned)Nn) ? c3 : 0u;
                x0 = xb[(size_t)c0 * CH + lane];
                x1 = xb[(size_t)c1 * CH + lane];
                x2 = xb[(size_t)c2 * CH + lane];
                x3 = xb[(size_t)c3 * CH + lane];
            }

            int bb = 0;
            while (true) {
                // phase A: read b+1 -> S, gather -> y, compute R with x
                {
                    if (bb == 2 && c + 2 < nchunks) {
                        const char* gs = (const char*)rec +
                            ((size_t)(segS + ((c + 2) << 5))) * 32 + lane * 16;
                        char* ls = (char*)recbuf + ((((c + 2) % 3) * 4 + w) << 10);
                        dma16(gs, ls);
                    }
                    int o = ((bb + 1) & 7) << 7;
                    Sa0 = *(const u32x4*)(rb + o);       Sb0 = *(const u32x2*)(rb + o + 16);
                    Sa1 = *(const u32x4*)(rb + o + 32);  Sb1 = *(const u32x2*)(rb + o + 48);
                    Sa2 = *(const u32x4*)(rb + o + 64);  Sb2 = *(const u32x2*)(rb + o + 80);
                    Sa3 = *(const u32x4*)(rb + o + 96);  Sb3 = *(const u32x2*)(rb + o + 112);
                    unsigned c0 = Sa0.x; c0 = (c0 < (unsigned)Nn) ? c0 : 0u;
                    unsigned c1 = Sa1.x; c1 = (c1 < (unsigned)Nn) ? c1 : 0u;
                    unsigned c2 = Sa2.x; c2 = (c2 < (unsigned)Nn) ? c2 : 0u;
                    unsigned c3 = Sa3.x; c3 = (c3 < (unsigned)Nn) ? c3 : 0u;
                    y0 = xb[(size_t)c0 * CH + lane];
                    y1 = xb[(size_t)c1 * CH + lane];
                    y2 = xb[(size_t)c2 * CH + lane];
                    y3 = xb[(size_t)c3 * CH + lane];
                    int qb = base + (bb << 2);
                    edge9(Ra0, Rb0, x0, qb + 0, Ash, w4, lane, a0, a1, a2, a3, a4, a5, a6, a7, a8, cnode, nextBnd, bnd1, bnd2, segE);
                    edge9(Ra1, Rb1, x1, qb + 1, Ash, w4, lane, a0, a1, a2, a3, a4, a5, a6, a7, a8, cnode, nextBnd, bnd1, bnd2, segE);
                    edge9(Ra2, Rb2, x2, qb + 2, Ash, w4, lane, a0, a1, a2, a3, a4, a5, a6, a7, a8, cnode, nextBnd, bnd1, bnd2, segE);
                    edge9(Ra3, Rb3, x3, qb + 3, Ash, w4, lane, a0, a1, a2, a3, a4, a5, a6, a7, a8, cnode, nextBnd, bnd1, bnd2, segE);
                }
                if (++bb >= nbat) break;
                // phase B: read b+1 -> R, gather -> x, compute S with y
                {
                    if (bb == 2 && c + 2 < nchunks) {
                        const char* gs = (const char*)rec +
                            ((size_t)(segS + ((c + 2) << 5))) * 32 + lane * 16;
                        char* ls = (char*)recbuf + ((((c + 2) % 3) * 4 + w) << 10);
                        dma16(gs, ls);
                    }
                    int o = ((bb + 1) & 7) << 7;
                    Ra0 = *(const u32x4*)(rb + o);       Rb0 = *(const u32x2*)(rb + o + 16);
                    Ra1 = *(const u32x4*)(rb + o + 32);  Rb1 = *(const u32x2*)(rb + o + 48);
                    Ra2 = *(const u32x4*)(rb + o + 64);  Rb2 = *(const u32x2*)(rb + o + 80);
                    Ra3 = *(const u32x4*)(rb + o + 96);  Rb3 = *(const u32x2*)(rb + o + 112);
                    unsigned c0 = Ra0.x; c0 = (c0 < (unsigned)Nn) ? c0 : 0u;
                    unsigned c1 = Ra1.x; c1 = (c1 < (unsigned)Nn) ? c1 : 0u;
                    unsigned c2 = Ra2.x; c2 = (c2 < (unsigned)Nn) ? c2 : 0u;
                    unsigned c3 = Ra3.x; c3 = (c3 < (unsigned)Nn) ? c3 : 0u;
                    x0 = xb[(size_t)c0 * CH + lane];
                    x1 = xb[(size_t)c1 * CH + lane];
                    x2 = xb[(size_t)c2 * CH + lane];
                    x3 = xb[(size_t)c3 * CH + lane];
                    int qb = base + (bb << 2);
                    edge9(Sa0, Sb0, y0, qb + 0, Ash, w4, lane, a0, a1, a2, a3, a4, a5, a6, a7, a8, cnode, nextBnd, bnd1, bnd2, segE);
                    edge9(Sa1, Sb1, y1, qb + 1, Ash, w4, lane, a0, a1, a2, a3, a4, a5, a6, a7, a8, cnode, nextBnd, bnd1, bnd2, segE);
                    edge9(Sa2, Sb2, y2, qb + 2, Ash, w4, lane, a0, a1, a2, a3, a4, a5, a6, a7, a8, cnode, nextBnd, bnd1, bnd2, segE);
                    edge9(Sa3, Sb3, y3, qb + 3, Ash, w4, lane, a0, a1, a2, a3, a4, a5, a6, a7, a8, cnode, nextBnd, bnd1, bnd2, segE);
                }
                if (++bb >= nbat) break;
            }
        }
    }
    while (cnode < 4)
        flushA(Ash, w4, lane, a0, a1, a2, a3, a4, a5, a6, a7, a8,
               cnode, nextBnd, bnd1, bnd2, segE);
    __syncthreads();

    // ---- GEMM: C[16x64] = A[16x576] @ W[576x64], wave w -> 16-col slice ----
    f32x4 C = {0, 0, 0, 0};
    int arow = lane & 15, g2 = lane >> 4;
    const unsigned short* ab = Ash + arow * LROW + g2 * 8;
    const bf16x8* wv = (const bf16x8*)wfb;
#pragma unroll
    for (int ks = 0; ks < 18; ++ks) {
        bf16x8 a = *(const bf16x8*)(ab + ks * 32);
        bf16x8 bfr = wv[(ks * 4 + w) * 64 + lane];
        C = __builtin_amdgcn_mfma_f32_16x16x32_bf16(a, bfr, C, 0, 0, 0);
    }
    float* ob = out + (size_t)n0 * CH + w * 16 + (lane & 15);
#pragma unroll
    for (int r = 0; r < 4; ++r) {
        int orow = g2 * 4 + r;
        if (n0 + orow < Nn) ob[orow * CH] = C[r];
    }
}

extern "C" void kernel_launch(void* const* d_in, const int* in_sizes, int n_in,
                              void* d_out, int out_size, void* d_ws, size_t ws_size,
                              hipStream_t stream) {
    const float* x   = (const float*)d_in[0];
    const int*   nbr = (const int*)d_in[1];
    const float* ff  = (const float*)d_in[2];
    const float* W   = (const float*)d_in[3];
    float* out = (float*)d_out;

    int Nn = in_sizes[0] / CH;   // 50000
    int E  = in_sizes[1] / 2;    // 1600000
    const int* row = nbr;
    const int* col = nbr + E;

    char* p = (char*)d_ws;
    auto alloc = [&](size_t bytes) -> void* {
        void* r = (void*)p;
        p += (bytes + 511) & ~(size_t)511;
        return r;
    };
    int* cnt    = (int*)alloc((size_t)Nn * 4);
    int* loc    = (int*)alloc((size_t)Nn * 4);
    int* csum   = (int*)alloc(1024);
    int* coff   = (int*)alloc(1024);
    int* starts = (int*)alloc((size_t)(Nn + 1) * 4);
    int* cur    = (int*)alloc((size_t)Nn * 4);
    unsigned* rec = (unsigned*)alloc((size_t)E * 32 + 4096);     // +pad for DMA overshoot
    unsigned short* xb  = (unsigned short*)alloc((size_t)Nn * CH * 2);
    unsigned short* wfb = (unsigned short*)alloc(72 * 64 * 8 * 2);

    (void)hipMemsetAsync(cnt, 0, (size_t)Nn * 4, stream);

    k_hist_xconv<<<2048, 256, 0, stream>>>(row, cnt, x, xb, E, Nn);

    int nch = (Nn + 255) / 256;  // 196
    k_scan1<<<nch, 256, 0, stream>>>(cnt, loc, csum, Nn);
    k_scan2<<<1, 256, 0, stream>>>(csum, coff, nch);
    k_scan3_wprep<<<nch, 256, 0, stream>>>(loc, coff, starts, cur, W, wfb, Nn, E);

    k_scatter<<<2048, 256, 0, stream>>>(row, col, ff, cur, rec, E, Nn);

    k_fused<<<(Nn + 15) / 16, 256, 0, stream>>>(xb, rec, starts, wfb, out, Nn);
}